// Round 7
// baseline (735.802 us; speedup 1.0000x reference)
//
#include <hip/hip_runtime.h>

// Problem constants
#define EMB 1024
#define NH 16
#define HD 64
#define SEQ 2048
#define BB 4

typedef __attribute__((ext_vector_type(8))) short bf8;   // 8 bf16 (4 VGPRs)
typedef __attribute__((ext_vector_type(4))) short bf4;   // 4 bf16 (2 VGPRs)
typedef __attribute__((ext_vector_type(4))) float f4;    // MFMA C/D frag

#define MFMA16(a, b, c) __builtin_amdgcn_mfma_f32_16x16x32_bf16((a), (b), (c), 0, 0, 0)

#if defined(__has_builtin)
#if __has_builtin(__builtin_amdgcn_mfma_f32_16x16x16_bf16_1k)
#define HAVE_MFMA16X16 1
#endif
#if __has_builtin(__builtin_amdgcn_exp2f)
#define EXP2F __builtin_amdgcn_exp2f
#endif
#if __has_builtin(__builtin_amdgcn_cvt_pk_bf16_f32)
#define HAVE_PK_BF16 1
#endif
#if __has_builtin(__builtin_amdgcn_perm)
#define HAVE_PERM 1
#endif
#endif
#ifndef EXP2F
#define EXP2F exp2f
#endif

__device__ inline f4 pv_mfma(bf4 a, bf4 b, f4 c) {
#ifdef HAVE_MFMA16X16
  return __builtin_amdgcn_mfma_f32_16x16x16_bf16_1k(a, b, c, 0, 0, 0);
#else
  bf8 av, bv;
  *(bf4*)&av = a;  ((int*)&av)[2] = 0; ((int*)&av)[3] = 0;
  *(bf4*)&bv = b;  ((int*)&bv)[2] = 0; ((int*)&bv)[3] = 0;
  return __builtin_amdgcn_mfma_f32_16x16x32_bf16(av, bv, c, 0, 0, 0);
#endif
}

// global -> LDS direct copy, 16B per lane (wave-uniform base + lane*16).
#define GLL16(g, l)                                                     \
  __builtin_amdgcn_global_load_lds(                                     \
      (__attribute__((address_space(1))) void*)(g),                     \
      (__attribute__((address_space(3))) void*)(l), 16, 0, 0)

__device__ inline unsigned short f2bf(float f) {
  union { float f; unsigned u; } v; v.f = f;
  unsigned u = v.u;
  u += 0x7fffu + ((u >> 16) & 1u);   // RNE
  return (unsigned short)(u >> 16);
}

// pack two fp32 -> bf16x2 dword (probabilities: no NaN/Inf).
// Defined-semantics paths only (R7: inline-asm cvt_pk produced NaN).
__device__ inline unsigned pkbf(float a, float b) {
#ifdef HAVE_PK_BF16
  typedef __attribute__((ext_vector_type(2))) __bf16 bf16x2;
  union { bf16x2 v; unsigned u; } c;
  c.v = __builtin_amdgcn_cvt_pk_bf16_f32(a, b);
  return c.u;
#elif defined(HAVE_PERM)
  union { float f; unsigned u; } ua, ub; ua.f = a; ub.f = b;
  // dst = {b'[31:16], a'[31:16]}; src0=b' (bytes 4-7), src1=a' (bytes 0-3)
  return __builtin_amdgcn_perm(ub.u + 0x8000u, ua.u + 0x8000u, 0x07060302u);
#else
  union { float f; unsigned u; } ua, ub; ua.f = a; ub.f = b;
  return ((ua.u + 0x8000u) >> 16) | ((ub.u + 0x8000u) & 0xFFFF0000u);
#endif
}

// ---------------- fp32 -> bf16 convert (memory-bound, all 3 inputs fused) ---
// xb/wqkvb/woutb are CONTIGUOUS in ws -> one output index stream.
// regions (float4 units): x [0,2097152) | w_qkv [..,2883584) | w_out [..,3145728)
__global__ void cvt_all(const float* __restrict__ x, const float* __restrict__ wq,
                        const float* __restrict__ wo, unsigned short* __restrict__ out) {
  int i = blockIdx.x * blockDim.x + threadIdx.x;
  float4 f;
  if (i < 2097152)      f = ((const float4*)x)[i];
  else if (i < 2883584) f = ((const float4*)wq)[i - 2097152];
  else                  f = ((const float4*)wo)[i - 2883584];
  ushort4 o;
  o.x = f2bf(f.x); o.y = f2bf(f.y); o.z = f2bf(f.z); o.w = f2bf(f.w);
  ((ushort4*)out)[i] = o;
}

// ---------------- BT GEMM: C[M,N] = A[M,K] * B[N,K]^T ----------------
// 128x128 tile, BK=32, 256 threads (4 waves). m97 structure.
// Columns n >= nsplit stored TRANSPOSED into vtb[(b*1024 + (n-nsplit))][2048].
template <bool OUTF32>
__global__ __launch_bounds__(256, 2) void gemm_bt(
    const unsigned short* __restrict__ A, const unsigned short* __restrict__ B,
    void* __restrict__ Cout, const float* __restrict__ bias,
    unsigned short* __restrict__ vtb,
    int M, int N, int K, int ldC, int nsplit) {
  __shared__ unsigned short la[128 * 32];
  __shared__ unsigned short lb[128 * 32];

  const int t = threadIdx.x;
  const int lane = t & 63;
  const int w = t >> 6;
  const int quad = lane >> 4;
  const int lcol = lane & 15;
  const int m0 = blockIdx.y * 128;
  const int n0 = blockIdx.x * 128;
  const int wm = (w & 1) * 64;
  const int wn = (w >> 1) * 64;

  f4 acc[4][4];
#pragma unroll
  for (int i = 0; i < 4; i++)
#pragma unroll
    for (int j = 0; j < 4; j++) acc[i][j] = (f4){0.f, 0.f, 0.f, 0.f};

  const int srow = t >> 2;
  const int scol = (t & 3) * 8;
  const unsigned short* gA = A + (size_t)(m0 + srow) * K + scol;
  const unsigned short* gB = B + (size_t)(n0 + srow) * K + scol;
  unsigned short* lA = la + t * 8;
  unsigned short* lB = lb + t * 8;

  for (int kt = 0; kt < K; kt += 32) {
    __syncthreads();
    GLL16(gA + kt, lA);
    GLL16(gA + kt + (size_t)64 * K, lA + 64 * 32);
    GLL16(gB + kt, lB);
    GLL16(gB + kt + (size_t)64 * K, lB + 64 * 32);
    __syncthreads();

    bf8 af[4], bfr[4];
#pragma unroll
    for (int i = 0; i < 4; i++) {
      af[i]  = *(const bf8*)&la[(wm + i * 16 + lcol) * 32 + quad * 8];
      bfr[i] = *(const bf8*)&lb[(wn + i * 16 + lcol) * 32 + quad * 8];
    }
#pragma unroll
    for (int i = 0; i < 4; i++)
#pragma unroll
      for (int j = 0; j < 4; j++)
        acc[i][j] = MFMA16(af[i], bfr[j], acc[i][j]);
  }

  if (!OUTF32 && n0 >= nsplit) {
#pragma unroll
    for (int i = 0; i < 4; i++) {
#pragma unroll
      for (int j = 0; j < 4; j++) {
        int f = n0 + wn + j * 16 + lcol - nsplit;      // 0..1023 = h*64+d
        int mg = m0 + wm + i * 16 + quad * 4;          // flat b*2048+s, s%4==0
        int bb = mg >> 11, ss = mg & 2047;
        ushort4 pk;
        pk.x = f2bf(acc[i][j][0]); pk.y = f2bf(acc[i][j][1]);
        pk.z = f2bf(acc[i][j][2]); pk.w = f2bf(acc[i][j][3]);
        *(ushort4*)&vtb[((size_t)(bb * 1024 + f)) * 2048 + ss] = pk;
      }
    }
  } else {
#pragma unroll
    for (int i = 0; i < 4; i++) {
#pragma unroll
      for (int j = 0; j < 4; j++) {
#pragma unroll
        for (int r = 0; r < 4; r++) {
          int m = m0 + wm + i * 16 + quad * 4 + r;
          int n = n0 + wn + j * 16 + lcol;
          if (OUTF32) {
            float v = acc[i][j][r] + (bias ? bias[n] : 0.f);
            ((float*)Cout)[(size_t)m * ldC + n] = v;
          } else {
            ((unsigned short*)Cout)[(size_t)m * ldC + n] = f2bf(acc[i][j][r]);
          }
        }
      }
    }
  }
}

// ---------------- flash attention, S^T orientation, FIXED-MAX softmax -------
// R11: attn is LDS-traffic / per-wave-ILP bound (R6: FETCH -82% via XCD
// swizzle but dur only -7%; VALU 60 / MFMA 34 / occupancy stuck; per-CU LDS
// read demand ~50B/cy + railed bank-conflict counter). K and V fragments are
// SHARED operands -- every wave re-reads the full K/V tile. Fix: each wave
// now owns 32 q-rows (two 16-col B-frag sets A/B); every kf/vf LDS read
// feeds 2 MFMAs -> LDS bytes per q-row HALVED, and per-wave ILP doubles
// (two independent softmax/PV chains). Block = 8 waves x 32 q = 256 q-rows.
// grid 512 blocks; XCD decode keeps all 8 q-tiles of one (b,h) on one XCD
// (K/V 4MB per XCD = L2-resident, preserved from R6).
#define SCALE_LOG2E 0.1803368801111244f  // (1/8) * log2(e)
#define BKEEP (-16.0f / SCALE_LOG2E)     // pre-divided: exp2((s+BKEEP)*c) = exp2(s*c-16)
#define BDROP (-1e30f / SCALE_LOG2E)     // -5.5e30, fits f32; exp2 -> 0

__global__ __launch_bounds__(512, 4) void attn_kernel(
    const unsigned short* __restrict__ qk, const unsigned short* __restrict__ vtg,
    const int* __restrict__ mask, unsigned short* __restrict__ outb) {
  // buffer stride 16384 shorts: [0..8191] K tile [key 0..127][d 0..63],
  // [8192..16383] V^T tile [d 0..63][key 0..127]; both XOR-swizzled chunks.
  __shared__ unsigned short kv[2 * 16384];
  __shared__ __align__(16) float bt[2][128];  // per-key bias/c

  const int t = threadIdx.x;
  const int lane = t & 63;
  const int w = t >> 6;                         // 0..7
  const int quad = lane >> 4;
  const int lcol = lane & 15;
  const int lx = lcol & 7;                      // read-side swizzle key

  // XCD-aware decode: flat id (x fastest). Same (b,h) group -> same id%8
  // residue -> same XCD (round-robin dispatch). 8 q-tiles per group.
  const int id = blockIdx.x + (blockIdx.y << 3) + (blockIdx.z << 7); // [0,512)
  const int g  = (id & 7) | ((id >> 6) << 3);   // (b,h) group [0,64)
  const int q0 = ((id >> 3) & 7) * 256;
  const int h = g & 15;
  const int b = g >> 4;

  const unsigned short* qbase = qk + (size_t)(b * SEQ) * 2048 + h * HD;
  const unsigned short* kbase = qbase + 1024;
  const unsigned short* vbase = vtg + (size_t)((b * 16 + h) * 64) * SEQ;

  // Q B-frags: two 16-col sets per wave. Lane holds Q[q][d=quad*8+j (+32)].
  const int qrA = q0 + w * 32 + lcol;
  const int qrB = qrA + 16;
  const bf8 qf0A = *(const bf8*)(qbase + (size_t)qrA * 2048 + quad * 8);
  const bf8 qf1A = *(const bf8*)(qbase + (size_t)qrA * 2048 + 32 + quad * 8);
  const bf8 qf0B = *(const bf8*)(qbase + (size_t)qrB * 2048 + quad * 8);
  const bf8 qf1B = *(const bf8*)(qbase + (size_t)qrB * 2048 + 32 + quad * 8);

  f4 oA[4], oB[4];   // O^T frags: lane holds O^T[d=16db+4quad+r][q]
#pragma unroll
  for (int db = 0; db < 4; db++) {
    oA[db] = (f4){0.f, 0.f, 0.f, 0.f};
    oB[db] = (f4){0.f, 0.f, 0.f, 0.f};
  }
  float lsumA = 0.f, lsumB = 0.f;

  // K staging: thread t covers key sr=t>>3 (sweep2: +64), swizzled d-chunk
  const int sr = t >> 3;                        // 0..63
  const int sc = ((t & 7) ^ (sr & 7)) * 8;
  const unsigned short* gk = kbase + (size_t)sr * 2048 + sc;  // + key*2048
  // V staging: thread t covers d=t>>4 (sweep2: +32), swizzled key-chunk
  const int vd = t >> 4;                        // 0..31
  const int vc8 = ((t & 15) ^ (vd & 7)) * 8;
  const unsigned short* gv = vbase + (size_t)vd * SEQ + vc8;  // + key

  const int NT = SEQ / 128;   // 16

  // prologue: stage tile 0 into buffer 0; bias tile 0; mask tile 1
  GLL16(gk, kv + t * 8);
  GLL16(gk + (size_t)64 * 2048, kv + 4096 + t * 8);
  GLL16(gv, kv + 8192 + t * 8);
  GLL16(gv + (size_t)32 * SEQ, kv + 12288 + t * 8);
  if (t < 128) bt[0][t] = mask[b * SEQ + t] ? BKEEP : BDROP;
  int pmv = (t < 128) ? mask[b * SEQ + 128 + t] : 0;

  for (int it = 0; it < NT; ++it) {
    const int cur = (it & 1) * 16384;
    __syncthreads();  // publishes tile it (drains GLL16 vmcnt) + bt[it&1]

    if (it + 1 < NT) {
      const int nxt = ((it + 1) & 1) * 16384;
      const size_t k1 = (size_t)(it + 1) * 128;
      GLL16(gk + k1 * 2048, kv + nxt + t * 8);
      GLL16(gk + (k1 + 64) * 2048, kv + nxt + 4096 + t * 8);
      GLL16(gv + k1, kv + nxt + 8192 + t * 8);
      GLL16(gv + (size_t)32 * SEQ + k1, kv + nxt + 12288 + t * 8);
      if (t < 128) bt[(it + 1) & 1][t] = pmv ? BKEEP : BDROP;
      int kn = (it + 2 < NT) ? (it + 2) * 128 : 0;
      pmv = (t < 128) ? mask[b * SEQ + kn + t] : 0;
    }

    const unsigned short* kcur = kv + cur;
    const unsigned short* vcur = kv + cur + 8192;
    const float* bcur = bt[it & 1];

#pragma unroll
    for (int hh = 0; hh < 2; hh++) {
      // S^T = K Q^T + bias/c : lane gets S'[q][key=hh*64+16kb+4quad+r]
      // kf0/kf1 read ONCE, used for both q-column sets.
      f4 sTA[4], sTB[4];
      __builtin_amdgcn_s_setprio(1);
#pragma unroll
      for (int kb = 0; kb < 4; kb++) {
        const unsigned short* krow = kcur + (hh * 64 + kb * 16 + lcol) * 64;
        bf8 kf0 = *(const bf8*)&krow[(quad ^ lx) * 8];
        bf8 kf1 = *(const bf8*)&krow[((4 + quad) ^ lx) * 8];
        f4 ab = *(const f4*)&bcur[hh * 64 + kb * 16 + quad * 4];
        f4 aA = MFMA16(kf0, qf0A, ab);
        aA = MFMA16(kf1, qf1A, aA);
        sTA[kb] = aA;
        f4 aB = MFMA16(kf0, qf0B, ab);
        aB = MFMA16(kf1, qf1B, aB);
        sTB[kb] = aB;
      }
      __builtin_amdgcn_s_setprio(0);

      // p = exp2((s + bias/c) * c); two independent chains
      bf4 pfragA[4], pfragB[4];
#pragma unroll
      for (int kb = 0; kb < 4; kb++) {
        float a0 = EXP2F(sTA[kb][0] * SCALE_LOG2E);
        float a1 = EXP2F(sTA[kb][1] * SCALE_LOG2E);
        float a2 = EXP2F(sTA[kb][2] * SCALE_LOG2E);
        float a3 = EXP2F(sTA[kb][3] * SCALE_LOG2E);
        lsumA += (a0 + a1) + (a2 + a3);
        union { unsigned u[2]; bf4 s; } ca;
        ca.u[0] = pkbf(a0, a1);
        ca.u[1] = pkbf(a2, a3);
        pfragA[kb] = ca.s;
        float b0 = EXP2F(sTB[kb][0] * SCALE_LOG2E);
        float b1 = EXP2F(sTB[kb][1] * SCALE_LOG2E);
        float b2 = EXP2F(sTB[kb][2] * SCALE_LOG2E);
        float b3 = EXP2F(sTB[kb][3] * SCALE_LOG2E);
        lsumB += (b0 + b1) + (b2 + b3);
        union { unsigned u[2]; bf4 s; } cb;
        cb.u[0] = pkbf(b0, b1);
        cb.u[1] = pkbf(b2, b3);
        pfragB[kb] = cb.s;
      }

      // PV: vf read ONCE, feeds both accumulator sets.
      __builtin_amdgcn_s_setprio(1);
#pragma unroll
      for (int db = 0; db < 4; db++) {
        const unsigned short* vrow = vcur + (db * 16 + lcol) * 128;
#pragma unroll
        for (int kb = 0; kb < 4; kb++) {
          int c = ((hh * 4 + kb) << 1) | (quad >> 1);
          bf4 vf = *(const bf4*)&vrow[(c ^ lx) * 8 + (quad & 1) * 4];
          oA[db] = pv_mfma(vf, pfragA[kb], oA[db]);
          oB[db] = pv_mfma(vf, pfragB[kb], oB[db]);
        }
      }
      __builtin_amdgcn_s_setprio(0);
    }
  }

  // final l reduction across quads (same q-row lives in lanes lcol+16*quad)
  lsumA += __shfl_xor(lsumA, 16);
  lsumA += __shfl_xor(lsumA, 32);
  lsumB += __shfl_xor(lsumB, 16);
  lsumB += __shfl_xor(lsumB, 32);
  float invA = 1.f / lsumA;
  float invB = 1.f / lsumB;
#pragma unroll
  for (int db = 0; db < 4; db++) {
    ushort4 pk;
    pk.x = f2bf(oA[db][0] * invA);
    pk.y = f2bf(oA[db][1] * invA);
    pk.z = f2bf(oA[db][2] * invA);
    pk.w = f2bf(oA[db][3] * invA);
    *(ushort4*)&outb[(size_t)(b * SEQ + qrA) * EMB + h * HD +
                     db * 16 + quad * 4] = pk;
    ushort4 pk2;
    pk2.x = f2bf(oB[db][0] * invB);
    pk2.y = f2bf(oB[db][1] * invB);
    pk2.z = f2bf(oB[db][2] * invB);
    pk2.w = f2bf(oB[db][3] * invB);
    *(ushort4*)&outb[(size_t)(b * SEQ + qrB) * EMB + h * HD +
                     db * 16 + quad * 4] = pk2;
  }
}

extern "C" void kernel_launch(void* const* d_in, const int* in_sizes, int n_in,
                              void* d_out, int out_size, void* d_ws, size_t ws_size,
                              hipStream_t stream) {
  const float* x     = (const float*)d_in[0];
  const float* w_qkv = (const float*)d_in[1];
  const float* w_out = (const float*)d_in[2];
  const float* b_out = (const float*)d_in[3];
  const int*   mask  = (const int*)d_in[4];

  char* ws = (char*)d_ws;
  unsigned short* xb    = (unsigned short*)(ws + 0);          // 16 MB [8192][1024]
  unsigned short* wqkvb = (unsigned short*)(ws + 16777216);   //  6 MB [3072][1024]
  unsigned short* woutb = (unsigned short*)(ws + 23068672);   //  2 MB [1024][1024]
  unsigned short* qkb   = (unsigned short*)(ws + 25165824);   // 32 MB [8192][2048] (Q|K)
  unsigned short* attnb = (unsigned short*)(ws + 58720256);   // 16 MB [8192][1024]
  unsigned short* vtb   = (unsigned short*)(ws + 75497472);   // 16 MB [4096][2048] V^T

  // one fused convert (xb|wqkvb|woutb are contiguous in ws)
  cvt_all<<<12288, 256, 0, stream>>>(x, w_qkv, w_out, (unsigned short*)ws);

  // QKV projection: Q,K -> qkb (ld 2048); V (n>=2048) -> vtb transposed
  gemm_bt<false><<<dim3(24, 64), 256, 0, stream>>>(
      xb, wqkvb, (void*)qkb, nullptr, vtb, 8192, 3072, 1024, 2048, 2048);

  // attention: 512-thread blocks, 256 q-rows (32/wave), KVBLK=128, XCD-swizzled
  attn_kernel<<<dim3(8, 16, 4), 512, 0, stream>>>(qkb, vtb, mask, attnb);

  // out projection + bias -> fp32 d_out
  gemm_bt<true><<<dim3(8, 64), 256, 0, stream>>>(
      attnb, woutb, d_out, b_out, nullptr, 8192, 1024, 1024, 1024, 1 << 30);
}

// Round 8
// 657.912 us; speedup vs baseline: 1.1184x; 1.1184x over previous
//
#include <hip/hip_runtime.h>

// Problem constants
#define EMB 1024
#define NH 16
#define HD 64
#define SEQ 2048
#define BB 4

typedef __attribute__((ext_vector_type(8))) short bf8;   // 8 bf16 (4 VGPRs)
typedef __attribute__((ext_vector_type(4))) short bf4;   // 4 bf16 (2 VGPRs)
typedef __attribute__((ext_vector_type(4))) float f4;    // MFMA C/D frag

#define MFMA16(a, b, c) __builtin_amdgcn_mfma_f32_16x16x32_bf16((a), (b), (c), 0, 0, 0)

#if defined(__has_builtin)
#if __has_builtin(__builtin_amdgcn_mfma_f32_16x16x16_bf16_1k)
#define HAVE_MFMA16X16 1
#endif
#if __has_builtin(__builtin_amdgcn_exp2f)
#define EXP2F __builtin_amdgcn_exp2f
#endif
#if __has_builtin(__builtin_amdgcn_cvt_pk_bf16_f32)
#define HAVE_PK_BF16 1
#endif
#if __has_builtin(__builtin_amdgcn_perm)
#define HAVE_PERM 1
#endif
#endif
#ifndef EXP2F
#define EXP2F exp2f
#endif

__device__ inline f4 pv_mfma(bf4 a, bf4 b, f4 c) {
#ifdef HAVE_MFMA16X16
  return __builtin_amdgcn_mfma_f32_16x16x16_bf16_1k(a, b, c, 0, 0, 0);
#else
  bf8 av, bv;
  *(bf4*)&av = a;  ((int*)&av)[2] = 0; ((int*)&av)[3] = 0;
  *(bf4*)&bv = b;  ((int*)&bv)[2] = 0; ((int*)&bv)[3] = 0;
  return __builtin_amdgcn_mfma_f32_16x16x32_bf16(av, bv, c, 0, 0, 0);
#endif
}

// global -> LDS direct copy, 16B per lane (wave-uniform base + lane*16).
#define GLL16(g, l)                                                     \
  __builtin_amdgcn_global_load_lds(                                     \
      (__attribute__((address_space(1))) void*)(g),                     \
      (__attribute__((address_space(3))) void*)(l), 16, 0, 0)

__device__ inline unsigned short f2bf(float f) {
  union { float f; unsigned u; } v; v.f = f;
  unsigned u = v.u;
  u += 0x7fffu + ((u >> 16) & 1u);   // RNE
  return (unsigned short)(u >> 16);
}

// pack two fp32 -> bf16x2 dword (probabilities: no NaN/Inf).
// Defined-semantics paths only (R7: inline-asm cvt_pk produced NaN).
__device__ inline unsigned pkbf(float a, float b) {
#ifdef HAVE_PK_BF16
  typedef __attribute__((ext_vector_type(2))) __bf16 bf16x2;
  union { bf16x2 v; unsigned u; } c;
  c.v = __builtin_amdgcn_cvt_pk_bf16_f32(a, b);
  return c.u;
#elif defined(HAVE_PERM)
  union { float f; unsigned u; } ua, ub; ua.f = a; ub.f = b;
  // dst = {b'[31:16], a'[31:16]}; src0=b' (bytes 4-7), src1=a' (bytes 0-3)
  return __builtin_amdgcn_perm(ub.u + 0x8000u, ua.u + 0x8000u, 0x07060302u);
#else
  union { float f; unsigned u; } ua, ub; ua.f = a; ub.f = b;
  return ((ua.u + 0x8000u) >> 16) | ((ub.u + 0x8000u) & 0xFFFF0000u);
#endif
}

// ---------------- fp32 -> bf16 convert (memory-bound, all 3 inputs fused) ---
// xb/wqkvb/woutb are CONTIGUOUS in ws -> one output index stream.
// regions (float4 units): x [0,2097152) | w_qkv [..,2883584) | w_out [..,3145728)
__global__ void cvt_all(const float* __restrict__ x, const float* __restrict__ wq,
                        const float* __restrict__ wo, unsigned short* __restrict__ out) {
  int i = blockIdx.x * blockDim.x + threadIdx.x;
  float4 f;
  if (i < 2097152)      f = ((const float4*)x)[i];
  else if (i < 2883584) f = ((const float4*)wq)[i - 2097152];
  else                  f = ((const float4*)wo)[i - 2883584];
  ushort4 o;
  o.x = f2bf(f.x); o.y = f2bf(f.y); o.z = f2bf(f.z); o.w = f2bf(f.w);
  ((ushort4*)out)[i] = o;
}

// ---------------- BT GEMM: C[M,N] = A[M,K] * B[N,K]^T ----------------
// 128x128 tile, BK=32, 256 threads (4 waves). m97 structure.
// R12: XCD-chunked block swizzle (m157/m204; +10% measured on this structure,
// m192): XCD x processes a CONTIGUOUS chunk of the grid -> A/B panel reuse
// lands in that XCD's L2. Requires grid%8==0 (1536, 512: both OK).
// Columns n >= nsplit stored TRANSPOSED into vtb[(b*1024 + (n-nsplit))][2048].
template <bool OUTF32>
__global__ __launch_bounds__(256, 2) void gemm_bt(
    const unsigned short* __restrict__ A, const unsigned short* __restrict__ B,
    void* __restrict__ Cout, const float* __restrict__ bias,
    unsigned short* __restrict__ vtb,
    int M, int N, int K, int ldC, int nsplit) {
  __shared__ unsigned short la[128 * 32];
  __shared__ unsigned short lb[128 * 32];

  const int t = threadIdx.x;
  const int lane = t & 63;
  const int w = t >> 6;
  const int quad = lane >> 4;
  const int lcol = lane & 15;

  // XCD swizzle: flat dispatch id -> chunked id (bijective, grid%8==0)
  const int nbx = gridDim.x;
  const int flat = blockIdx.y * nbx + blockIdx.x;
  const int nper = (nbx * gridDim.y) >> 3;
  const int sw = (flat & 7) * nper + (flat >> 3);
  const int m0 = (sw / nbx) * 128;
  const int n0 = (sw % nbx) * 128;

  const int wm = (w & 1) * 64;
  const int wn = (w >> 1) * 64;

  f4 acc[4][4];
#pragma unroll
  for (int i = 0; i < 4; i++)
#pragma unroll
    for (int j = 0; j < 4; j++) acc[i][j] = (f4){0.f, 0.f, 0.f, 0.f};

  const int srow = t >> 2;
  const int scol = (t & 3) * 8;
  const unsigned short* gA = A + (size_t)(m0 + srow) * K + scol;
  const unsigned short* gB = B + (size_t)(n0 + srow) * K + scol;
  unsigned short* lA = la + t * 8;
  unsigned short* lB = lb + t * 8;

  for (int kt = 0; kt < K; kt += 32) {
    __syncthreads();
    GLL16(gA + kt, lA);
    GLL16(gA + kt + (size_t)64 * K, lA + 64 * 32);
    GLL16(gB + kt, lB);
    GLL16(gB + kt + (size_t)64 * K, lB + 64 * 32);
    __syncthreads();

    bf8 af[4], bfr[4];
#pragma unroll
    for (int i = 0; i < 4; i++) {
      af[i]  = *(const bf8*)&la[(wm + i * 16 + lcol) * 32 + quad * 8];
      bfr[i] = *(const bf8*)&lb[(wn + i * 16 + lcol) * 32 + quad * 8];
    }
#pragma unroll
    for (int i = 0; i < 4; i++)
#pragma unroll
      for (int j = 0; j < 4; j++)
        acc[i][j] = MFMA16(af[i], bfr[j], acc[i][j]);
  }

  if (!OUTF32 && n0 >= nsplit) {
#pragma unroll
    for (int i = 0; i < 4; i++) {
#pragma unroll
      for (int j = 0; j < 4; j++) {
        int f = n0 + wn + j * 16 + lcol - nsplit;      // 0..1023 = h*64+d
        int mg = m0 + wm + i * 16 + quad * 4;          // flat b*2048+s, s%4==0
        int bb = mg >> 11, ss = mg & 2047;
        ushort4 pk;
        pk.x = f2bf(acc[i][j][0]); pk.y = f2bf(acc[i][j][1]);
        pk.z = f2bf(acc[i][j][2]); pk.w = f2bf(acc[i][j][3]);
        *(ushort4*)&vtb[((size_t)(bb * 1024 + f)) * 2048 + ss] = pk;
      }
    }
  } else {
#pragma unroll
    for (int i = 0; i < 4; i++) {
#pragma unroll
      for (int j = 0; j < 4; j++) {
#pragma unroll
        for (int r = 0; r < 4; r++) {
          int m = m0 + wm + i * 16 + quad * 4 + r;
          int n = n0 + wn + j * 16 + lcol;
          if (OUTF32) {
            float v = acc[i][j][r] + (bias ? bias[n] : 0.f);
            ((float*)Cout)[(size_t)m * ldC + n] = v;
          } else {
            ((unsigned short*)Cout)[(size_t)m * ldC + n] = f2bf(acc[i][j][r]);
          }
        }
      }
    }
  }
}

// ---------------- flash attention, S^T orientation, FIXED-MAX softmax -------
// R12: V is L2-resident after the XCD swizzle (R6: FETCH 139->24.8MB), so V
// staging through LDS is pure overhead (Common-mistake #7 / m169). V frags
// now read DIRECTLY from global vtb (L2/L1 hit): LDS 66->33KB -> 4 blocks/CU,
// all 1024 blocks resident (occupancy 39 -> ~90%), LDS read traffic per iter
// halved, GLL16s per iter 4->2, and register pressure DROPS (R7 lesson: the
// VGPR budget is the binding box -- no doubled state).
// Global V address = de-swizzled verified LDS read: staging pre-XOR'd source
// chunk by (row&7), so direct-global uses PLAIN chunk c (no ^lx).
// grid: (16,16,4) x 512 threads; wave w: q rows [q0+w*16, +16).
#define SCALE_LOG2E 0.1803368801111244f  // (1/8) * log2(e)
#define BKEEP (-16.0f / SCALE_LOG2E)     // pre-divided: exp2((s+BKEEP)*c) = exp2(s*c-16)
#define BDROP (-1e30f / SCALE_LOG2E)     // -5.5e30, fits f32; exp2 -> 0

__global__ __launch_bounds__(512, 4) void attn_kernel(
    const unsigned short* __restrict__ qk, const unsigned short* __restrict__ vtg,
    const int* __restrict__ mask, unsigned short* __restrict__ outb) {
  // buffer stride 8192 shorts: K tile [key 0..127][d 0..63], XOR-swizzled chunks
  __shared__ unsigned short kv[2 * 8192];
  __shared__ __align__(16) float bt[2][128];  // per-key bias/c

  const int t = threadIdx.x;
  const int lane = t & 63;
  const int w = t >> 6;                         // 0..7
  const int quad = lane >> 4;
  const int lcol = lane & 15;
  const int lx = lcol & 7;                      // read-side swizzle key (K only)

  // XCD-aware decode: flat id (x fastest). Same (b,h) group -> same id%8
  // residue -> same XCD (round-robin dispatch). 16 q-tiles per group.
  const int id = blockIdx.x + (blockIdx.y << 4) + (blockIdx.z << 8);  // [0,1024)
  const int g  = (id & 7) + ((id >> 7) << 3);   // (b,h) group [0,64)
  const int q0 = ((id >> 3) & 15) * 128;
  const int h = g & 15;
  const int b = g >> 4;

  const unsigned short* qbase = qk + (size_t)(b * SEQ) * 2048 + h * HD;
  const unsigned short* kbase = qbase + 1024;
  const unsigned short* vbase = vtg + (size_t)((b * 16 + h) * 64) * SEQ;

  // Q B-frag: lane holds Q[n=q=lcol][k=d=quad*8+j (+32)]
  const int qrow = q0 + w * 16 + lcol;
  const bf8 qf0 = *(const bf8*)(qbase + (size_t)qrow * 2048 + quad * 8);
  const bf8 qf1 = *(const bf8*)(qbase + (size_t)qrow * 2048 + 32 + quad * 8);

  f4 o[4];   // O^T frags: lane holds O^T[d=16db+4quad+r][q=lcol]
#pragma unroll
  for (int db = 0; db < 4; db++) o[db] = (f4){0.f, 0.f, 0.f, 0.f};
  float lsum = 0.f;   // lane-partial softmax denominator (x 2^-16)

  // K staging: thread t covers key sr=t>>3 (sweep2: +64), swizzled d-chunk
  const int sr = t >> 3;                        // 0..63
  const int sc = ((t & 7) ^ (sr & 7)) * 8;
  const unsigned short* gk = kbase + (size_t)sr * 2048 + sc;  // + key*2048

  // V read base: lane owns V^T row d = db*16+lcol (direct from global/L2)
  const unsigned short* gvr = vbase + (size_t)lcol * SEQ;

  const int NT = SEQ / 128;   // 16

  // prologue: stage K tile 0 into buffer 0; bias tile 0; mask tile 1
  GLL16(gk, kv + t * 8);
  GLL16(gk + (size_t)64 * 2048, kv + 4096 + t * 8);
  if (t < 128) bt[0][t] = mask[b * SEQ + t] ? BKEEP : BDROP;
  int pmv = (t < 128) ? mask[b * SEQ + 128 + t] : 0;

  for (int it = 0; it < NT; ++it) {
    const int cur = (it & 1) * 8192;
    __syncthreads();  // publishes K tile it (drains GLL16 vmcnt) + bt[it&1]

    if (it + 1 < NT) {
      const int nxt = ((it + 1) & 1) * 8192;
      const size_t k1 = (size_t)(it + 1) * 128;
      GLL16(gk + k1 * 2048, kv + nxt + t * 8);
      GLL16(gk + (k1 + 64) * 2048, kv + nxt + 4096 + t * 8);
      if (t < 128) bt[(it + 1) & 1][t] = pmv ? BKEEP : BDROP;
      int kn = (it + 2 < NT) ? (it + 2) * 128 : 0;
      pmv = (t < 128) ? mask[b * SEQ + kn + t] : 0;
    }

    const unsigned short* kcur = kv + cur;
    const float* bcur = bt[it & 1];

#pragma unroll
    for (int hh = 0; hh < 2; hh++) {
      // S^T = K Q^T + bias/c : lane gets S'[q=lcol][key=hh*64+16kb+4quad+r]
      f4 sT[4];
      __builtin_amdgcn_s_setprio(1);
#pragma unroll
      for (int kb = 0; kb < 4; kb++) {
        const unsigned short* krow = kcur + (hh * 64 + kb * 16 + lcol) * 64;
        bf8 kf0 = *(const bf8*)&krow[(quad ^ lx) * 8];
        bf8 kf1 = *(const bf8*)&krow[((4 + quad) ^ lx) * 8];
        f4 a = *(const f4*)&bcur[hh * 64 + kb * 16 + quad * 4];
        a = MFMA16(kf0, qf0, a);
        a = MFMA16(kf1, qf1, a);
        sT[kb] = a;
      }
      __builtin_amdgcn_s_setprio(0);

      // p = exp2((s + bias/c) * c); accumulate lane-partial l
      bf4 pfrag[4];
#pragma unroll
      for (int kb = 0; kb < 4; kb++) {
        float p0 = EXP2F(sT[kb][0] * SCALE_LOG2E);
        float p1 = EXP2F(sT[kb][1] * SCALE_LOG2E);
        float p2 = EXP2F(sT[kb][2] * SCALE_LOG2E);
        float p3 = EXP2F(sT[kb][3] * SCALE_LOG2E);
        lsum += (p0 + p1) + (p2 + p3);
        union { unsigned u[2]; bf4 s; } cv;
        cv.u[0] = pkbf(p0, p1);
        cv.u[1] = pkbf(p2, p3);
        pfrag[kb] = cv.s;
      }

      // PV: O^T[d][q] += V^T A-frag x P B-frag; V read direct from global
      // (L2-hit). Plain chunk index c -- the LDS XOR existed only for banks.
      __builtin_amdgcn_s_setprio(1);
#pragma unroll
      for (int db = 0; db < 4; db++) {
        const unsigned short* vrow = gvr + (size_t)(db * 16) * SEQ + it * 128;
#pragma unroll
        for (int kb = 0; kb < 4; kb++) {
          int c = ((hh * 4 + kb) << 1) | (quad >> 1);
          bf4 vf = *(const bf4*)&vrow[c * 8 + (quad & 1) * 4];
          o[db] = pv_mfma(vf, pfrag[kb], o[db]);
        }
      }
      __builtin_amdgcn_s_setprio(0);
    }
  }

  // final l reduction across quads (same q-row lives in lanes lcol+16*quad)
  lsum += __shfl_xor(lsum, 16);
  lsum += __shfl_xor(lsum, 32);
  float inv = 1.f / lsum;
#pragma unroll
  for (int db = 0; db < 4; db++) {
    ushort4 pk;
    pk.x = f2bf(o[db][0] * inv);
    pk.y = f2bf(o[db][1] * inv);
    pk.z = f2bf(o[db][2] * inv);
    pk.w = f2bf(o[db][3] * inv);
    *(ushort4*)&outb[(size_t)(b * SEQ + q0 + w * 16 + lcol) * EMB + h * HD +
                     db * 16 + quad * 4] = pk;
  }
}

extern "C" void kernel_launch(void* const* d_in, const int* in_sizes, int n_in,
                              void* d_out, int out_size, void* d_ws, size_t ws_size,
                              hipStream_t stream) {
  const float* x     = (const float*)d_in[0];
  const float* w_qkv = (const float*)d_in[1];
  const float* w_out = (const float*)d_in[2];
  const float* b_out = (const float*)d_in[3];
  const int*   mask  = (const int*)d_in[4];

  char* ws = (char*)d_ws;
  unsigned short* xb    = (unsigned short*)(ws + 0);          // 16 MB [8192][1024]
  unsigned short* wqkvb = (unsigned short*)(ws + 16777216);   //  6 MB [3072][1024]
  unsigned short* woutb = (unsigned short*)(ws + 23068672);   //  2 MB [1024][1024]
  unsigned short* qkb   = (unsigned short*)(ws + 25165824);   // 32 MB [8192][2048] (Q|K)
  unsigned short* attnb = (unsigned short*)(ws + 58720256);   // 16 MB [8192][1024]
  unsigned short* vtb   = (unsigned short*)(ws + 75497472);   // 16 MB [4096][2048] V^T

  // one fused convert (xb|wqkvb|woutb are contiguous in ws)
  cvt_all<<<12288, 256, 0, stream>>>(x, w_qkv, w_out, (unsigned short*)ws);

  // QKV projection: Q,K -> qkb (ld 2048); V (n>=2048) -> vtb transposed
  gemm_bt<false><<<dim3(24, 64), 256, 0, stream>>>(
      xb, wqkvb, (void*)qkb, nullptr, vtb, 8192, 3072, 1024, 2048, 2048);

  // attention: 512-thread blocks, 128 q-rows, KVBLK=128, V direct from L2
  attn_kernel<<<dim3(16, 16, 4), 512, 0, stream>>>(qkb, vtb, mask, attnb);

  // out projection + bias -> fp32 d_out
  gemm_bt<true><<<dim3(8, 64), 256, 0, stream>>>(
      attnb, woutb, d_out, b_out, nullptr, 8192, 1024, 1024, 1024, 1 << 30);
}

// Round 9
// 306.415 us; speedup vs baseline: 2.4013x; 2.1471x over previous
//
#include <hip/hip_runtime.h>

// Problem constants
#define EMB 1024
#define NH 16
#define HD 64
#define SEQ 2048
#define BB 4

typedef __attribute__((ext_vector_type(8))) short bf8;   // 8 bf16 (4 VGPRs)
typedef __attribute__((ext_vector_type(4))) short bf4;   // 4 bf16 (2 VGPRs)
typedef __attribute__((ext_vector_type(4))) float f4;    // MFMA C/D frag

#define MFMA16(a, b, c) __builtin_amdgcn_mfma_f32_16x16x32_bf16((a), (b), (c), 0, 0, 0)

#if defined(__has_builtin)
#if __has_builtin(__builtin_amdgcn_mfma_f32_16x16x16_bf16_1k)
#define HAVE_MFMA16X16 1
#endif
#if __has_builtin(__builtin_amdgcn_exp2f)
#define EXP2F __builtin_amdgcn_exp2f
#endif
#if __has_builtin(__builtin_amdgcn_cvt_pk_bf16_f32)
#define HAVE_PK_BF16 1
#endif
#if __has_builtin(__builtin_amdgcn_perm)
#define HAVE_PERM 1
#endif
#endif
#ifndef EXP2F
#define EXP2F exp2f
#endif

__device__ inline f4 pv_mfma(bf4 a, bf4 b, f4 c) {
#ifdef HAVE_MFMA16X16
  return __builtin_amdgcn_mfma_f32_16x16x16_bf16_1k(a, b, c, 0, 0, 0);
#else
  bf8 av, bv;
  *(bf4*)&av = a;  ((int*)&av)[2] = 0; ((int*)&av)[3] = 0;
  *(bf4*)&bv = b;  ((int*)&bv)[2] = 0; ((int*)&bv)[3] = 0;
  return __builtin_amdgcn_mfma_f32_16x16x32_bf16(av, bv, c, 0, 0, 0);
#endif
}

// global -> LDS direct copy, 16B per lane (wave-uniform base + lane*16).
#define GLL16(g, l)                                                     \
  __builtin_amdgcn_global_load_lds(                                     \
      (__attribute__((address_space(1))) void*)(g),                     \
      (__attribute__((address_space(3))) void*)(l), 16, 0, 0)

__device__ inline unsigned short f2bf(float f) {
  union { float f; unsigned u; } v; v.f = f;
  unsigned u = v.u;
  u += 0x7fffu + ((u >> 16) & 1u);   // RNE
  return (unsigned short)(u >> 16);
}

// pack two fp32 -> bf16x2 dword (probabilities: no NaN/Inf).
// Defined-semantics paths only (R7: inline-asm cvt_pk produced NaN).
__device__ inline unsigned pkbf(float a, float b) {
#ifdef HAVE_PK_BF16
  typedef __attribute__((ext_vector_type(2))) __bf16 bf16x2;
  union { bf16x2 v; unsigned u; } c;
  c.v = __builtin_amdgcn_cvt_pk_bf16_f32(a, b);
  return c.u;
#elif defined(HAVE_PERM)
  union { float f; unsigned u; } ua, ub; ua.f = a; ub.f = b;
  // dst = {b'[31:16], a'[31:16]}; src0=b' (bytes 4-7), src1=a' (bytes 0-3)
  return __builtin_amdgcn_perm(ub.u + 0x8000u, ua.u + 0x8000u, 0x07060302u);
#else
  union { float f; unsigned u; } ua, ub; ua.f = a; ub.f = b;
  return ((ua.u + 0x8000u) >> 16) | ((ub.u + 0x8000u) & 0xFFFF0000u);
#endif
}

#define SCALE_LOG2E 0.1803368801111244f  // (1/8) * log2(e)

// ---------------- fp32 -> bf16 convert (memory-bound, all 3 inputs fused) ---
// xb/wqkvb/woutb are CONTIGUOUS in ws -> one output index stream.
// regions (float4 units): x [0,2097152) | w_qkv [..,2883584) | w_out [..,3145728)
__global__ void cvt_all(const float* __restrict__ x, const float* __restrict__ wq,
                        const float* __restrict__ wo, unsigned short* __restrict__ out) {
  int i = blockIdx.x * blockDim.x + threadIdx.x;
  float4 f;
  if (i < 2097152)      f = ((const float4*)x)[i];
  else if (i < 2883584) f = ((const float4*)wq)[i - 2097152];
  else                  f = ((const float4*)wo)[i - 2883584];
  ushort4 o;
  o.x = f2bf(f.x); o.y = f2bf(f.y); o.z = f2bf(f.z); o.w = f2bf(f.w);
  ((ushort4*)out)[i] = o;
}

// ---------------- BT GEMM: C[M,N] = A[M,K] * B[N,K]^T ----------------
// 128x128 tile, BK=32, 256 threads (4 waves). m97 structure.
// XCD-chunked block swizzle (m157/m204): contiguous grid chunk per XCD.
// R9: K-columns (n in [1024,2048), !OUTF32) are pre-scaled by SCALE_LOG2E at
// the epilogue, so attn's softmax is a bare exp2 (scale folded into K).
// Columns n >= nsplit stored TRANSPOSED into vtb[(b*1024 + (n-nsplit))][2048].
template <bool OUTF32>
__global__ __launch_bounds__(256, 2) void gemm_bt(
    const unsigned short* __restrict__ A, const unsigned short* __restrict__ B,
    void* __restrict__ Cout, const float* __restrict__ bias,
    unsigned short* __restrict__ vtb,
    int M, int N, int K, int ldC, int nsplit) {
  __shared__ unsigned short la[128 * 32];
  __shared__ unsigned short lb[128 * 32];

  const int t = threadIdx.x;
  const int lane = t & 63;
  const int w = t >> 6;
  const int quad = lane >> 4;
  const int lcol = lane & 15;

  // XCD swizzle: flat dispatch id -> chunked id (bijective, grid%8==0)
  const int nbx = gridDim.x;
  const int flat = blockIdx.y * nbx + blockIdx.x;
  const int nper = (nbx * gridDim.y) >> 3;
  const int sw = (flat & 7) * nper + (flat >> 3);
  const int m0 = (sw / nbx) * 128;
  const int n0 = (sw % nbx) * 128;

  const int wm = (w & 1) * 64;
  const int wn = (w >> 1) * 64;

  f4 acc[4][4];
#pragma unroll
  for (int i = 0; i < 4; i++)
#pragma unroll
    for (int j = 0; j < 4; j++) acc[i][j] = (f4){0.f, 0.f, 0.f, 0.f};

  const int srow = t >> 2;
  const int scol = (t & 3) * 8;
  const unsigned short* gA = A + (size_t)(m0 + srow) * K + scol;
  const unsigned short* gB = B + (size_t)(n0 + srow) * K + scol;
  unsigned short* lA = la + t * 8;
  unsigned short* lB = lb + t * 8;

  for (int kt = 0; kt < K; kt += 32) {
    __syncthreads();
    GLL16(gA + kt, lA);
    GLL16(gA + kt + (size_t)64 * K, lA + 64 * 32);
    GLL16(gB + kt, lB);
    GLL16(gB + kt + (size_t)64 * K, lB + 64 * 32);
    __syncthreads();

    bf8 af[4], bfr[4];
#pragma unroll
    for (int i = 0; i < 4; i++) {
      af[i]  = *(const bf8*)&la[(wm + i * 16 + lcol) * 32 + quad * 8];
      bfr[i] = *(const bf8*)&lb[(wn + i * 16 + lcol) * 32 + quad * 8];
    }
#pragma unroll
    for (int i = 0; i < 4; i++)
#pragma unroll
      for (int j = 0; j < 4; j++)
        acc[i][j] = MFMA16(af[i], bfr[j], acc[i][j]);
  }

  if (!OUTF32 && n0 >= nsplit) {
#pragma unroll
    for (int i = 0; i < 4; i++) {
#pragma unroll
      for (int j = 0; j < 4; j++) {
        int f = n0 + wn + j * 16 + lcol - nsplit;      // 0..1023 = h*64+d
        int mg = m0 + wm + i * 16 + quad * 4;          // flat b*2048+s, s%4==0
        int bb = mg >> 11, ss = mg & 2047;
        ushort4 pk;
        pk.x = f2bf(acc[i][j][0]); pk.y = f2bf(acc[i][j][1]);
        pk.z = f2bf(acc[i][j][2]); pk.w = f2bf(acc[i][j][3]);
        *(ushort4*)&vtb[((size_t)(bb * 1024 + f)) * 2048 + ss] = pk;
      }
    }
  } else {
#pragma unroll
    for (int i = 0; i < 4; i++) {
#pragma unroll
      for (int j = 0; j < 4; j++) {
        int n = n0 + wn + j * 16 + lcol;
        // K-columns of the QKV projection carry the softmax scale.
        const float scl = (!OUTF32 && n >= 1024) ? SCALE_LOG2E : 1.f;
#pragma unroll
        for (int r = 0; r < 4; r++) {
          int m = m0 + wm + i * 16 + quad * 4 + r;
          if (OUTF32) {
            float v = acc[i][j][r] + (bias ? bias[n] : 0.f);
            ((float*)Cout)[(size_t)m * ldC + n] = v;
          } else {
            ((unsigned short*)Cout)[(size_t)m * ldC + n] = f2bf(acc[i][j][r] * scl);
          }
        }
      }
    }
  }
}

// ---------------- flash attention, S^T orientation, FIXED-MAX softmax -------
// R9 = R6-exact revert (the proven 134us config) + scale-folded-into-K.
// R6 config: 512 threads / 8 waves, 128 q-rows per block, KVBLK=128 (two
// 64-key halves per barrier reusing sT/pfrag regs), K+V staged in LDS
// (66KB, 2 blocks/CU), XCD decode keeps all 16 q-tiles of one (b,h) on one
// XCD (K/V L2-resident: FETCH 139->24.8MB), setprio around MFMA clusters.
// R7 lesson: VGPR budget is the binding box (no doubled per-wave state).
// R8 lesson: V must stay in LDS (per-fragment global loads = latency death);
// K XOR-swizzle is conflict-free (R8: SQ_LDS_BANK_CONFLICT==0 without V).
// Softmax: S' = b + (K*c)Q^T via C-init, p = exp2(S') directly (c folded
// into K at the GEMM; b = -16 keep / -1e30 drop; 2^-16 cancels in norm).
#define BKEEP (-16.0f)
#define BDROP (-1e30f)

__global__ __launch_bounds__(512, 4) void attn_kernel(
    const unsigned short* __restrict__ qk, const unsigned short* __restrict__ vtg,
    const int* __restrict__ mask, unsigned short* __restrict__ outb) {
  // buffer stride 16384 shorts: [0..8191] K tile [key 0..127][d 0..63],
  // [8192..16383] V^T tile [d 0..63][key 0..127]; both XOR-swizzled chunks.
  __shared__ unsigned short kv[2 * 16384];
  __shared__ __align__(16) float bt[2][128];  // per-key bias: keep? -16 : -1e30

  const int t = threadIdx.x;
  const int lane = t & 63;
  const int w = t >> 6;                         // 0..7
  const int quad = lane >> 4;
  const int lcol = lane & 15;
  const int lx = lcol & 7;                      // read-side swizzle key

  // XCD-aware decode: flat id (x fastest). Same (b,h) group -> same id%8
  // residue -> same XCD (round-robin dispatch). 16 q-tiles per group.
  const int id = blockIdx.x + (blockIdx.y << 4) + (blockIdx.z << 8);  // [0,1024)
  const int g  = (id & 7) + ((id >> 7) << 3);   // (b,h) group [0,64)
  const int q0 = ((id >> 3) & 15) * 128;
  const int h = g & 15;
  const int b = g >> 4;

  const unsigned short* qbase = qk + (size_t)(b * SEQ) * 2048 + h * HD;
  const unsigned short* kbase = qbase + 1024;
  const unsigned short* vbase = vtg + (size_t)((b * 16 + h) * 64) * SEQ;

  // Q B-frag: lane holds Q[n=q=lcol][k=d=quad*8+j (+32)]
  const int qrow = q0 + w * 16 + lcol;
  const bf8 qf0 = *(const bf8*)(qbase + (size_t)qrow * 2048 + quad * 8);
  const bf8 qf1 = *(const bf8*)(qbase + (size_t)qrow * 2048 + 32 + quad * 8);

  f4 o[4];   // O^T frags: lane holds O^T[d=16db+4quad+r][q=lcol]
#pragma unroll
  for (int db = 0; db < 4; db++) o[db] = (f4){0.f, 0.f, 0.f, 0.f};
  float lsum = 0.f;   // lane-partial softmax denominator (x 2^-16)

  // K staging: thread t covers key sr=t>>3 (sweep2: +64), swizzled d-chunk
  const int sr = t >> 3;                        // 0..63
  const int sc = ((t & 7) ^ (sr & 7)) * 8;
  const unsigned short* gk = kbase + (size_t)sr * 2048 + sc;  // + key*2048
  // V staging: thread t covers d=t>>4 (sweep2: +32), swizzled key-chunk
  const int vd = t >> 4;                        // 0..31
  const int vc8 = ((t & 15) ^ (vd & 7)) * 8;
  const unsigned short* gv = vbase + (size_t)vd * SEQ + vc8;  // + key

  const int NT = SEQ / 128;   // 16

  // prologue: stage tile 0 into buffer 0; bias tile 0; mask tile 1
  GLL16(gk, kv + t * 8);
  GLL16(gk + (size_t)64 * 2048, kv + 4096 + t * 8);
  GLL16(gv, kv + 8192 + t * 8);
  GLL16(gv + (size_t)32 * SEQ, kv + 12288 + t * 8);
  if (t < 128) bt[0][t] = mask[b * SEQ + t] ? BKEEP : BDROP;
  int pmv = (t < 128) ? mask[b * SEQ + 128 + t] : 0;

  for (int it = 0; it < NT; ++it) {
    const int cur = (it & 1) * 16384;
    __syncthreads();  // publishes tile it (drains GLL16 vmcnt) + bt[it&1]

    if (it + 1 < NT) {
      const int nxt = ((it + 1) & 1) * 16384;
      const size_t k1 = (size_t)(it + 1) * 128;
      GLL16(gk + k1 * 2048, kv + nxt + t * 8);
      GLL16(gk + (k1 + 64) * 2048, kv + nxt + 4096 + t * 8);
      GLL16(gv + k1, kv + nxt + 8192 + t * 8);
      GLL16(gv + (size_t)32 * SEQ + k1, kv + nxt + 12288 + t * 8);
      if (t < 128) bt[(it + 1) & 1][t] = pmv ? BKEEP : BDROP;
      int kn = (it + 2 < NT) ? (it + 2) * 128 : 0;
      pmv = (t < 128) ? mask[b * SEQ + kn + t] : 0;
    }

    const unsigned short* kcur = kv + cur;
    const unsigned short* vcur = kv + cur + 8192;
    const float* bcur = bt[it & 1];

#pragma unroll
    for (int hh = 0; hh < 2; hh++) {
      // S' = b + (K*c) Q^T : lane gets S'[q=lcol][key=hh*64+16kb+4quad+r]
      f4 sT[4];
      __builtin_amdgcn_s_setprio(1);
#pragma unroll
      for (int kb = 0; kb < 4; kb++) {
        const unsigned short* krow = kcur + (hh * 64 + kb * 16 + lcol) * 64;
        bf8 kf0 = *(const bf8*)&krow[(quad ^ lx) * 8];
        bf8 kf1 = *(const bf8*)&krow[((4 + quad) ^ lx) * 8];
        f4 a = *(const f4*)&bcur[hh * 64 + kb * 16 + quad * 4];
        a = MFMA16(kf0, qf0, a);
        a = MFMA16(kf1, qf1, a);
        sT[kb] = a;
      }
      __builtin_amdgcn_s_setprio(0);

      // p = exp2(S') (scale folded into K, bias via C-init); lane-partial l
      bf4 pfrag[4];
#pragma unroll
      for (int kb = 0; kb < 4; kb++) {
        float p0 = EXP2F(sT[kb][0]);
        float p1 = EXP2F(sT[kb][1]);
        float p2 = EXP2F(sT[kb][2]);
        float p3 = EXP2F(sT[kb][3]);
        lsum += (p0 + p1) + (p2 + p3);
        union { unsigned u[2]; bf4 s; } cv;
        cv.u[0] = pkbf(p0, p1);
        cv.u[1] = pkbf(p2, p3);
        pfrag[kb] = cv.s;
      }

      // PV: O^T[d][q] += V^T A-frag x P B-frag (swizzled vt read, 128-key rows)
      __builtin_amdgcn_s_setprio(1);
#pragma unroll
      for (int db = 0; db < 4; db++) {
        const unsigned short* vrow = vcur + (db * 16 + lcol) * 128;
#pragma unroll
        for (int kb = 0; kb < 4; kb++) {
          int c = ((hh * 4 + kb) << 1) | (quad >> 1);
          bf4 vf = *(const bf4*)&vrow[(c ^ lx) * 8 + (quad & 1) * 4];
          o[db] = pv_mfma(vf, pfrag[kb], o[db]);
        }
      }
      __builtin_amdgcn_s_setprio(0);
    }
  }

  // final l reduction across quads (same q-row lives in lanes lcol+16*quad)
  lsum += __shfl_xor(lsum, 16);
  lsum += __shfl_xor(lsum, 32);
  float inv = 1.f / lsum;
#pragma unroll
  for (int db = 0; db < 4; db++) {
    ushort4 pk;
    pk.x = f2bf(o[db][0] * inv);
    pk.y = f2bf(o[db][1] * inv);
    pk.z = f2bf(o[db][2] * inv);
    pk.w = f2bf(o[db][3] * inv);
    *(ushort4*)&outb[(size_t)(b * SEQ + q0 + w * 16 + lcol) * EMB + h * HD +
                     db * 16 + quad * 4] = pk;
  }
}

extern "C" void kernel_launch(void* const* d_in, const int* in_sizes, int n_in,
                              void* d_out, int out_size, void* d_ws, size_t ws_size,
                              hipStream_t stream) {
  const float* x     = (const float*)d_in[0];
  const float* w_qkv = (const float*)d_in[1];
  const float* w_out = (const float*)d_in[2];
  const float* b_out = (const float*)d_in[3];
  const int*   mask  = (const int*)d_in[4];

  char* ws = (char*)d_ws;
  unsigned short* xb    = (unsigned short*)(ws + 0);          // 16 MB [8192][1024]
  unsigned short* wqkvb = (unsigned short*)(ws + 16777216);   //  6 MB [3072][1024]
  unsigned short* woutb = (unsigned short*)(ws + 23068672);   //  2 MB [1024][1024]
  unsigned short* qkb   = (unsigned short*)(ws + 25165824);   // 32 MB [8192][2048] (Q|K)
  unsigned short* attnb = (unsigned short*)(ws + 58720256);   // 16 MB [8192][1024]
  unsigned short* vtb   = (unsigned short*)(ws + 75497472);   // 16 MB [4096][2048] V^T

  // one fused convert (xb|wqkvb|woutb are contiguous in ws)
  cvt_all<<<12288, 256, 0, stream>>>(x, w_qkv, w_out, (unsigned short*)ws);

  // QKV projection: Q,K -> qkb (ld 2048, K pre-scaled); V (n>=2048) -> vtb
  gemm_bt<false><<<dim3(24, 64), 256, 0, stream>>>(
      xb, wqkvb, (void*)qkb, nullptr, vtb, 8192, 3072, 1024, 2048, 2048);

  // attention: 512-thread blocks, 128 q-rows, KVBLK=128, XCD-swizzled
  attn_kernel<<<dim3(16, 16, 4), 512, 0, stream>>>(qkb, vtb, mask, attnb);

  // out projection + bias -> fp32 d_out
  gemm_bt<true><<<dim3(8, 64), 256, 0, stream>>>(
      attnb, woutb, d_out, b_out, nullptr, 8192, 1024, 1024, 1024, 1 << 30);
}